// Round 17
// baseline (4618.104 us; speedup 1.0000x reference)
//
#include <hip/hip_runtime.h>
#include <hip/hip_fp16.h>

#define BB 8
#define SS 2048
#define EE 1024
#define NHH 4
#define DHH 256

typedef _Float16 f16x2 __attribute__((ext_vector_type(2)));
typedef _Float16 f16x8 __attribute__((ext_vector_type(8)));
typedef float f32x4 __attribute__((ext_vector_type(4)));

__device__ __forceinline__ __half2 u2h2(unsigned int u) {
  union { unsigned int u; __half2 h; } c; c.u = u; return c.h;
}
__device__ __forceinline__ unsigned int h2u(__half2 h) {
  union { unsigned int u; __half2 h; } c; c.h = h; return c.u;
}

// ---------------------------------------------------------------------------
// Gates projection GEMM v2 (round-16 verbatim, verified): pair-merged MFMA.
// Output: gx f16, layout [S][B][NH][4*DH] = [i f z o]
// ---------------------------------------------------------------------------
__global__ __launch_bounds__(256) void gates_gemm2(
    const float* __restrict__ x, const float* __restrict__ conv_w,
    const float* __restrict__ conv_b,
    const float* __restrict__ fgw, const float* __restrict__ igw,
    const float* __restrict__ zgw, const float* __restrict__ ogw,
    __half* __restrict__ gx)
{
  __shared__ float Xs[8][11][33];      // [b][si][kk]  (halo 3)
  __shared__ __half As[2][64][40];     // [pair][row][k]
  __shared__ __half Bs[2][128][40];    // [pair][col][k]

  const int tid = threadIdx.x;
  const int mt  = blockIdx.x;          // 0..255
  const int nt2 = blockIdx.y;          // 0..3
  const int h   = blockIdx.z;          // 0..3
  const int s0  = mt << 3;
  const int n0  = nt2 << 7;

  const float* W0 = (n0 < 256) ? fgw : igw;   // pair0
  const float* W1 = (n0 < 256) ? zgw : ogw;   // pair1
  const int oobase = n0 & 255;

  const int w = tid >> 6, l = tid & 63;
  const int lrow = l & 15, kq = l >> 4;
  const int koff = kq << 3;

  f32x4 acc[2][2][4] = {};

  for (int d0 = 0; d0 < DHH; d0 += 32) {
    const int ebase = h * DHH + d0;

    for (int i = tid; i < 8 * 11 * 32; i += 256) {
      int kk = i & 31, rest = i >> 5;
      int b = rest / 11, si = rest - b * 11;
      int sg = s0 - 3 + si;
      float v = 0.f;
      if (sg >= 0) v = x[((size_t)b * SS + sg) * EE + ebase + kk];
      Xs[b][si][kk] = v;
    }
    for (int i = tid; i < 2 * 128 * 32; i += 256) {
      int p = i >> 12;
      int rem = i & 4095;
      int col = rem >> 5, k = rem & 31;
      const float* Wp = p ? W1 : W0;
      int oo = oobase + col;
      Bs[p][col][k] = __float2half(Wp[((size_t)h * DHH + oo) * DHH + d0 + k]);
    }
    __syncthreads();

    for (int i = tid; i < 2 * 64 * 32; i += 256) {
      int p = i >> 11;
      int rem = i & 2047;
      int kk = rem & 31, r = rem >> 5;
      int sl = r >> 3, b = r & 7;
      if (p == 0) {
        int e = ebase + kk;
        float xc = conv_b[e];
        xc = fmaf(Xs[b][sl + 0][kk], conv_w[0 * EE + e], xc);
        xc = fmaf(Xs[b][sl + 1][kk], conv_w[1 * EE + e], xc);
        xc = fmaf(Xs[b][sl + 2][kk], conv_w[2 * EE + e], xc);
        xc = fmaf(Xs[b][sl + 3][kk], conv_w[3 * EE + e], xc);
        float sg = 1.f / (1.f + __expf(-xc));
        As[0][r][kk] = __float2half(xc * sg);
      } else {
        As[1][r][kk] = __float2half(Xs[b][sl + 3][kk]);
      }
    }
    __syncthreads();

#pragma unroll
    for (int p = 0; p < 2; ++p) {
#pragma unroll
      for (int ct = 0; ct < 2; ++ct) {
        f16x8 bfrag = *(const f16x8*)&Bs[p][w * 32 + ct * 16 + lrow][koff];
#pragma unroll
        for (int mtl = 0; mtl < 4; ++mtl) {
          f16x8 afrag = *(const f16x8*)&As[p][mtl * 16 + lrow][koff];
          acc[p][ct][mtl] =
              __builtin_amdgcn_mfma_f32_16x16x32_f16(afrag, bfrag, acc[p][ct][mtl], 0, 0, 0);
        }
      }
    }
    __syncthreads();
  }

#pragma unroll
  for (int p = 0; p < 2; ++p) {
#pragma unroll
    for (int ct = 0; ct < 2; ++ct) {
#pragma unroll
      for (int mtl = 0; mtl < 4; ++mtl) {
#pragma unroll
        for (int j = 0; j < 4; ++j) {
          int row_loc = mtl * 16 + kq * 4 + j;
          int grow = mt * 64 + row_loc;
          int colg = n0 + w * 32 + ct * 16 + lrow;
          gx[(size_t)grow * 4096 + h * 1024 + p * 512 + colg] =
              __float2half(acc[p][ct][mtl][j]);
        }
      }
    }
  }
}

// ---------------------------------------------------------------------------
// sLSTM scan v7: v4's MFMA matvec (6 reg + 2 LDS N-tiles, proven no-spill)
// + v5's raw barriers (lgkmcnt-only: no vmcnt drain, gx prefetch stays in
// flight) + v5's unmasked broadcast A (no zero-fill movs / exec toggles).
// One WG (512 thr, 8 waves) per chain. Wave w owns cols [w*128,+128).
// A rows all identical (y broadcast); D row 0 taken from lanes 0..15 reg 0.
// Dynamic LDS: 131072 (ldsB) + 1024 (ypub) + 4096 (rawb) = 136192 B.
// ---------------------------------------------------------------------------
__global__ __launch_bounds__(512)
void slstm_scan7(
    const float* __restrict__ rk,    // (NH, DH, 4*DH)
    const float* __restrict__ rb,    // (NH, 4, DH)
    const __half* __restrict__ gx,   // [S][B][NH][1024]
    float* __restrict__ out)         // (B, S, E)
{
  extern __shared__ unsigned char smem[];
  uint4* ldsB  = (uint4*)smem;                 // [8w][2j][8kt][64l] = 131072 B
  __half* ypub = (__half*)(smem + 131072);     // [2][256]
  float* rawb  = (float*)(smem + 132096);      // [1024]

  const int t = threadIdx.x;
  const int w = t >> 6, l = t & 63;
  const int lrow = l & 15, lkq = l >> 4;
  const int b = blockIdx.x >> 2, h = blockIdx.x & 3;
  const float* Rh = rk + (size_t)h * DHH * 1024;
  const int n0w = w << 7;

  // B-fragments for N-tiles 0..5 into registers (AGPR-resident, MFMA-direct)
  f16x8 wB[6][8];
#pragma unroll
  for (int nt = 0; nt < 6; ++nt) {
    const int col = n0w + nt * 16 + lrow;
#pragma unroll
    for (int kt = 0; kt < 8; ++kt) {
      f16x8 f;
#pragma unroll
      for (int i = 0; i < 8; ++i) {
        const int k = kt * 32 + lkq * 8 + i;
        f[i] = (_Float16)Rh[(size_t)k * 1024 + col];
      }
      wB[nt][kt] = f;
    }
  }
  // N-tiles 6..7 into LDS, fragment order
  for (int j = 0; j < 2; ++j) {
    const int col = n0w + (6 + j) * 16 + lrow;
    for (int kt = 0; kt < 8; ++kt) {
      f16x8 f;
      for (int i = 0; i < 8; ++i) {
        const int k = kt * 32 + lkq * 8 + i;
        f[i] = (_Float16)Rh[(size_t)k * 1024 + col];
      }
      *(f16x8*)&ldsB[((w * 2 + j) * 8 + kt) * 64 + l] = f;
    }
  }

  // state-thread setup (t < 256 owns dim d = t)
  const int d = t & 255;
  float rb0 = 0.f, rb1 = 0.f, rb2 = 0.f, rb3 = 0.f;
  if (t < 256) {
    rb0 = rb[h * 1024 + d];
    rb1 = rb[h * 1024 + 256 + d];
    rb2 = rb[h * 1024 + 512 + d];
    rb3 = rb[h * 1024 + 768 + d];
    ypub[d] = __float2half(0.f);
    ypub[256 + d] = __float2half(0.f);
  }
  __syncthreads();

  float cst = 0.f, nst = 0.f, mst = 0.f;
  const size_t gxstep = (size_t)BB * NHH * 1024;
  const __half* gp = gx + ((size_t)b * NHH + h) * 1024;
  float cx0 = 0.f, cx1 = 0.f, cx2 = 0.f, cx3 = 0.f;
  __half nh0 = __float2half(0.f), nh1 = nh0, nh2 = nh0, nh3 = nh0;
  if (t < 256) {
    cx0 = __half2float(gp[d]);
    cx1 = __half2float(gp[256 + d]);
    cx2 = __half2float(gp[512 + d]);
    cx3 = __half2float(gp[768 + d]);
    const __half* p1 = gp + gxstep;
    nh0 = p1[d]; nh1 = p1[256 + d]; nh2 = p1[512 + d]; nh3 = p1[768 + d];
  }

  int cur = 0;
  for (int st = 0; st < SS; ++st) {
    // issue prefetch for step st+2 (in flight across raw barriers)
    __half p0 = nh0, p1v = nh1, p2 = nh2, p3 = nh3;
    if (t < 256) {
      const int sp = (st + 2 < SS) ? st + 2 : SS - 1;
      const __half* pp = gp + (size_t)sp * gxstep;
      p0 = pp[d]; p1v = pp[256 + d]; p2 = pp[512 + d]; p3 = pp[768 + d];
    }

    const __half* yc = ypub + cur * 256;
    f32x4 a0 = {}, a1 = {}, a2 = {}, a3 = {}, a4 = {}, a5 = {}, a6 = {}, a7 = {};
#pragma unroll
    for (int kt = 0; kt < 8; ++kt) {
      // unmasked broadcast: all lanes load the same 16B y-slice; all 16 A
      // rows identical -> row 0 of D is the matvec result
      f16x8 A = *(const f16x8*)(yc + kt * 32 + lkq * 8);
      a0 = __builtin_amdgcn_mfma_f32_16x16x32_f16(A, wB[0][kt], a0, 0, 0, 0);
      a1 = __builtin_amdgcn_mfma_f32_16x16x32_f16(A, wB[1][kt], a1, 0, 0, 0);
      a2 = __builtin_amdgcn_mfma_f32_16x16x32_f16(A, wB[2][kt], a2, 0, 0, 0);
      a3 = __builtin_amdgcn_mfma_f32_16x16x32_f16(A, wB[3][kt], a3, 0, 0, 0);
      a4 = __builtin_amdgcn_mfma_f32_16x16x32_f16(A, wB[4][kt], a4, 0, 0, 0);
      a5 = __builtin_amdgcn_mfma_f32_16x16x32_f16(A, wB[5][kt], a5, 0, 0, 0);
      f16x8 b6 = *(const f16x8*)&ldsB[((w * 2 + 0) * 8 + kt) * 64 + l];
      f16x8 b7 = *(const f16x8*)&ldsB[((w * 2 + 1) * 8 + kt) * 64 + l];
      a6 = __builtin_amdgcn_mfma_f32_16x16x32_f16(A, b6, a6, 0, 0, 0);
      a7 = __builtin_amdgcn_mfma_f32_16x16x32_f16(A, b7, a7, 0, 0, 0);
    }
    if (l < 16) {
      rawb[n0w +   0 + l] = a0[0];
      rawb[n0w +  16 + l] = a1[0];
      rawb[n0w +  32 + l] = a2[0];
      rawb[n0w +  48 + l] = a3[0];
      rawb[n0w +  64 + l] = a4[0];
      rawb[n0w +  80 + l] = a5[0];
      rawb[n0w +  96 + l] = a6[0];
      rawb[n0w + 112 + l] = a7[0];
    }

    // b1: raw ready — LDS-only ordering, no vmcnt drain (v5-proven pattern)
    asm volatile("s_waitcnt lgkmcnt(0)" ::: "memory");
    __builtin_amdgcn_s_barrier();

    if (t < 256) {
      float iv = rawb[d]       + cx0 + rb0;
      float fv = rawb[256 + d] + cx1 + rb1;
      float zv = rawb[512 + d] + cx2 + rb2;
      float ov = rawb[768 + d] + cx3 + rb3;

      float ea = __expf(-fabsf(fv));
      float ls = fminf(fv, 0.f) - __logf(1.f + ea);    // log_sigmoid(fv)
      float lfm = mst + ls;
      float mn = fmaxf(iv, lfm);
      float ig = __expf(iv - mn);
      float fg = __expf(lfm - mn);
      float pz = __expf(-2.f * fabsf(zv));
      float tm = __fdividef(1.f - pz, 1.f + pz);
      float th = (zv < 0.f) ? -tm : tm;                // tanh(zv)
      cst = fg * cst + ig * th;
      nst = fg * nst + ig;
      float og = __fdividef(1.f, 1.f + __expf(-ov));   // sigmoid(ov)
      float y = og * __fdividef(cst, nst);
      mst = mn;

      out[((size_t)b * SS + st) * EE + h * DHH + d] = y;
      ypub[(cur ^ 1) * 256 + d] = __float2half(y);
    }

    // b2: y ready
    asm volatile("s_waitcnt lgkmcnt(0)" ::: "memory");
    __builtin_amdgcn_s_barrier();

    cur ^= 1;
    cx0 = __half2float(nh0); cx1 = __half2float(nh1);
    cx2 = __half2float(nh2); cx3 = __half2float(nh3);
    nh0 = p0; nh1 = p1v; nh2 = p2; nh3 = p3;
  }
}

// ---------------------------------------------------------------------------
// GroupNorm over DH per (b,s,h), in place on out. One wave = one head.
// ---------------------------------------------------------------------------
__global__ __launch_bounds__(256) void groupnorm(
    float* __restrict__ y, const float* __restrict__ gnw)
{
  const int row = blockIdx.x;
  const int t = threadIdx.x;
  float4 v = ((const float4*)y)[(size_t)row * 256 + t];
  float s = v.x + v.y + v.z + v.w;
  float q = v.x * v.x + v.y * v.y + v.z * v.z + v.w * v.w;
#pragma unroll
  for (int mask = 1; mask < 64; mask <<= 1) {
    s += __shfl_xor(s, mask, 64);
    q += __shfl_xor(q, mask, 64);
  }
  float mu = s * (1.f / 256.f);
  float var = q * (1.f / 256.f) - mu * mu;
  float rs = rsqrtf(var + 1e-5f);
  float4 g = ((const float4*)gnw)[t];
  float4 o;
  o.x = (v.x - mu) * rs * g.x;
  o.y = (v.y - mu) * rs * g.y;
  o.z = (v.z - mu) * rs * g.z;
  o.w = (v.w - mu) * rs * g.w;
  ((float4*)y)[(size_t)row * 256 + t] = o;
}

extern "C" void kernel_launch(void* const* d_in, const int* in_sizes, int n_in,
                              void* d_out, int out_size, void* d_ws, size_t ws_size,
                              hipStream_t stream) {
  const float* x      = (const float*)d_in[0];
  const float* conv_w = (const float*)d_in[1];
  const float* conv_b = (const float*)d_in[2];
  const float* fgw    = (const float*)d_in[3];
  const float* igw    = (const float*)d_in[4];
  const float* zgw    = (const float*)d_in[5];
  const float* ogw    = (const float*)d_in[6];
  const float* rk     = (const float*)d_in[7];
  const float* rb     = (const float*)d_in[8];
  const float* gnw    = (const float*)d_in[9];
  float* out = (float*)d_out;
  __half* gx = (__half*)d_ws;   // [S][B][NH][1024] f16 = 134217728 B

  dim3 g1(256, 4, 4);
  gates_gemm2<<<g1, 256, 0, stream>>>(x, conv_w, conv_b, fgw, igw, zgw, ogw, gx);

  const int scan_lds = 131072 + 1024 + 4096;
  (void)hipFuncSetAttribute(reinterpret_cast<const void*>(slstm_scan7),
                            hipFuncAttributeMaxDynamicSharedMemorySize, scan_lds);
  slstm_scan7<<<32, 512, scan_lds, stream>>>(rk, rb, gx, out);

  groupnorm<<<BB * SS, 256, 0, stream>>>(out, gnw);
}

// Round 18
// 4303.810 us; speedup vs baseline: 1.0730x; 1.0730x over previous
//
#include <hip/hip_runtime.h>
#include <hip/hip_fp16.h>

#define BB 8
#define SS 2048
#define EE 1024
#define NHH 4
#define DHH 256

typedef _Float16 f16x2 __attribute__((ext_vector_type(2)));
typedef _Float16 f16x8 __attribute__((ext_vector_type(8)));
typedef float f32x4 __attribute__((ext_vector_type(4)));

__device__ __forceinline__ __half2 u2h2(unsigned int u) {
  union { unsigned int u; __half2 h; } c; c.u = u; return c.h;
}
__device__ __forceinline__ unsigned int h2u(__half2 h) {
  union { unsigned int u; __half2 h; } c; c.h = h; return c.u;
}
__device__ __forceinline__ f16x2 u2f(unsigned int u) {
  union { unsigned int u; f16x2 f; } c; c.u = u; return c.f;
}
__device__ __forceinline__ unsigned int pack2(float a, float b) {
  f16x2 f; f.x = (_Float16)a; f.y = (_Float16)b;
  union { f16x2 f; unsigned int u; } c; c.f = f; return c.u;
}
__device__ __forceinline__ float fdot2u(unsigned int w, unsigned int y, float acc) {
#if __has_builtin(__builtin_amdgcn_fdot2)
  return __builtin_amdgcn_fdot2(u2f(w), u2f(y), acc, false);
#else
  __half2 a = u2h2(w), b = u2h2(y);
  return acc + __low2float(a) * __low2float(b) + __high2float(a) * __high2float(b);
#endif
}

// ---------------------------------------------------------------------------
// Weight pre-pack: rk (f32) -> per-thread-ordered f16 uint4 chunks for the
// scan's L2-streamed gates. Layout: wpk[h][36 chunks][512 t] (uint4).
// Chunk c: c<4 -> gate0 j=12+c; c<20 -> gate2 j=c-4; else gate3 j=c-20.
// Thread t: d=t>>1, par=t&1, k0 = par*128 + j*8; col = g*256+d.
// Total 4*36*512*16 B = 1179648 B (L2-resident, shared per head).
// ---------------------------------------------------------------------------
__global__ __launch_bounds__(256) void pack_w(
    const float* __restrict__ rk, uint4* __restrict__ wpk)
{
  int idx = blockIdx.x * 256 + threadIdx.x;
  if (idx >= 4 * 36 * 512) return;
  int t = idx & 511;
  int c = (idx >> 9) % 36;
  int h = idx / (36 * 512);
  int d = t >> 1, par = t & 1, kbase = par << 7;
  int g, j;
  if (c < 4)       { g = 0; j = 12 + c; }
  else if (c < 20) { g = 2; j = c - 4; }
  else             { g = 3; j = c - 20; }
  int k0 = kbase + j * 8;
  int col = g * 256 + d;
  const float* Rh = rk + (size_t)h * DHH * 1024;
  uint4 u;
  u.x = pack2(Rh[(size_t)(k0 + 0) * 1024 + col], Rh[(size_t)(k0 + 1) * 1024 + col]);
  u.y = pack2(Rh[(size_t)(k0 + 2) * 1024 + col], Rh[(size_t)(k0 + 3) * 1024 + col]);
  u.z = pack2(Rh[(size_t)(k0 + 4) * 1024 + col], Rh[(size_t)(k0 + 5) * 1024 + col]);
  u.w = pack2(Rh[(size_t)(k0 + 6) * 1024 + col], Rh[(size_t)(k0 + 7) * 1024 + col]);
  wpk[idx] = u;
}

// ---------------------------------------------------------------------------
// Gates projection GEMM v2 (round-16 verbatim, verified): pair-merged MFMA.
// Output: gx f16, layout [S][B][NH][4*DH] = [i f z o]
// ---------------------------------------------------------------------------
__global__ __launch_bounds__(256) void gates_gemm2(
    const float* __restrict__ x, const float* __restrict__ conv_w,
    const float* __restrict__ conv_b,
    const float* __restrict__ fgw, const float* __restrict__ igw,
    const float* __restrict__ zgw, const float* __restrict__ ogw,
    __half* __restrict__ gx)
{
  __shared__ float Xs[8][11][33];
  __shared__ __half As[2][64][40];
  __shared__ __half Bs[2][128][40];

  const int tid = threadIdx.x;
  const int mt  = blockIdx.x;
  const int nt2 = blockIdx.y;
  const int h   = blockIdx.z;
  const int s0  = mt << 3;
  const int n0  = nt2 << 7;

  const float* W0 = (n0 < 256) ? fgw : igw;
  const float* W1 = (n0 < 256) ? zgw : ogw;
  const int oobase = n0 & 255;

  const int w = tid >> 6, l = tid & 63;
  const int lrow = l & 15, kq = l >> 4;
  const int koff = kq << 3;

  f32x4 acc[2][2][4] = {};

  for (int d0 = 0; d0 < DHH; d0 += 32) {
    const int ebase = h * DHH + d0;

    for (int i = tid; i < 8 * 11 * 32; i += 256) {
      int kk = i & 31, rest = i >> 5;
      int b = rest / 11, si = rest - b * 11;
      int sg = s0 - 3 + si;
      float v = 0.f;
      if (sg >= 0) v = x[((size_t)b * SS + sg) * EE + ebase + kk];
      Xs[b][si][kk] = v;
    }
    for (int i = tid; i < 2 * 128 * 32; i += 256) {
      int p = i >> 12;
      int rem = i & 4095;
      int col = rem >> 5, k = rem & 31;
      const float* Wp = p ? W1 : W0;
      int oo = oobase + col;
      Bs[p][col][k] = __float2half(Wp[((size_t)h * DHH + oo) * DHH + d0 + k]);
    }
    __syncthreads();

    for (int i = tid; i < 2 * 64 * 32; i += 256) {
      int p = i >> 11;
      int rem = i & 2047;
      int kk = rem & 31, r = rem >> 5;
      int sl = r >> 3, b = r & 7;
      if (p == 0) {
        int e = ebase + kk;
        float xc = conv_b[e];
        xc = fmaf(Xs[b][sl + 0][kk], conv_w[0 * EE + e], xc);
        xc = fmaf(Xs[b][sl + 1][kk], conv_w[1 * EE + e], xc);
        xc = fmaf(Xs[b][sl + 2][kk], conv_w[2 * EE + e], xc);
        xc = fmaf(Xs[b][sl + 3][kk], conv_w[3 * EE + e], xc);
        float sg = 1.f / (1.f + __expf(-xc));
        As[0][r][kk] = __float2half(xc * sg);
      } else {
        As[1][r][kk] = __float2half(Xs[b][sl + 3][kk]);
      }
    }
    __syncthreads();

#pragma unroll
    for (int p = 0; p < 2; ++p) {
#pragma unroll
      for (int ct = 0; ct < 2; ++ct) {
        f16x8 bfrag = *(const f16x8*)&Bs[p][w * 32 + ct * 16 + lrow][koff];
#pragma unroll
        for (int mtl = 0; mtl < 4; ++mtl) {
          f16x8 afrag = *(const f16x8*)&As[p][mtl * 16 + lrow][koff];
          acc[p][ct][mtl] =
              __builtin_amdgcn_mfma_f32_16x16x32_f16(afrag, bfrag, acc[p][ct][mtl], 0, 0, 0);
        }
      }
    }
    __syncthreads();
  }

#pragma unroll
  for (int p = 0; p < 2; ++p) {
#pragma unroll
    for (int ct = 0; ct < 2; ++ct) {
#pragma unroll
      for (int mtl = 0; mtl < 4; ++mtl) {
#pragma unroll
        for (int j = 0; j < 4; ++j) {
          int row_loc = mtl * 16 + kq * 4 + j;
          int grow = mt * 64 + row_loc;
          int colg = n0 + w * 32 + ct * 16 + lrow;
          gx[(size_t)grow * 4096 + h * 1024 + p * 512 + colg] =
              __float2half(acc[p][ct][mtl][j]);
        }
      }
    }
  }
}

// ---------------------------------------------------------------------------
// sLSTM scan v8: round-6 structure with 3-way weight sourcing sized to the
// TRUE arch-register budget (48 reg dwords, no AGPR pressure):
//   gate0 chunks 0..11 -> 48 dwords in arch VGPRs
//   gate1 (all 16 chunks) -> LDS wl4 [16][512] uint4 = 131072 B
//   gate0 chunks 12..15, gate2, gate3 -> streamed from wpk (L2-hot packed
//   f16, coalesced uint4 loads, no y-dependency -> compiler hoists freely)
// Lane map, y exchange, state update: round-6 verbatim.
// Dynamic LDS: 131072 + 1024 (ypub x2) = 132096 B
// ---------------------------------------------------------------------------
__global__
__attribute__((amdgpu_flat_work_group_size(512, 512), amdgpu_waves_per_eu(1)))
void slstm_scan8(
    const float* __restrict__ rk,    // (NH, DH, 4*DH)
    const float* __restrict__ rb,    // (NH, 4, DH)
    const __half* __restrict__ gx,   // [S][B][NH][1024]
    const uint4* __restrict__ wpk,   // [4][36][512] packed f16 chunks
    float* __restrict__ out)         // (B, S, E)
{
  extern __shared__ unsigned char smem[];
  uint4* wl4   = (uint4*)smem;                      // [16][512]
  __half* ypub = (__half*)(smem + 131072);          // [2][256]

  const int t = threadIdx.x;
  const int b = blockIdx.x >> 2, h = blockIdx.x & 3;
  const int d = t >> 1, par = t & 1;
  const int kbase = par << 7;                       // 0 or 128
  const float* Rh = rk + (size_t)h * DHH * 1024;
  const uint4* wgh = wpk + (size_t)h * 36 * 512;

  // gate0 chunks 0..11: 48 dwords in arch VGPRs
  unsigned int wv[48];
#pragma unroll
  for (int pp = 0; pp < 48; ++pp) {
    int k = kbase + 2 * pp;
    wv[pp] = pack2(Rh[(size_t)k * 1024 + d], Rh[(size_t)(k + 1) * 1024 + d]);
  }
  // gate1 -> LDS
  {
    const int col = 256 + d;
    for (int q = 0; q < 16; ++q) {
      uint4 u;
      int k = kbase + 8 * q;
      u.x = pack2(Rh[(size_t)(k + 0) * 1024 + col], Rh[(size_t)(k + 1) * 1024 + col]);
      u.y = pack2(Rh[(size_t)(k + 2) * 1024 + col], Rh[(size_t)(k + 3) * 1024 + col]);
      u.z = pack2(Rh[(size_t)(k + 4) * 1024 + col], Rh[(size_t)(k + 5) * 1024 + col]);
      u.w = pack2(Rh[(size_t)(k + 6) * 1024 + col], Rh[(size_t)(k + 7) * 1024 + col]);
      wl4[q * 512 + t] = u;
    }
  }

  float rbv[4];
#pragma unroll
  for (int g = 0; g < 4; ++g) rbv[g] = rb[h * 1024 + g * 256 + d];

  float c = 0.f, n = 0.f, m = 0.f;
  if (t < 256) { ypub[t] = __float2half(0.f); ypub[256 + t] = __float2half(0.f); }
  __syncthreads();

  int cur = 0;
  const __half* pg = gx + ((size_t)b * NHH + h) * 1024;
  float cx[4];
#pragma unroll
  for (int g = 0; g < 4; ++g) cx[g] = __half2float(pg[g * 256 + d]);
  const size_t out_base = ((size_t)b * SS) * EE + h * DHH + d;

  for (int st = 0; st < SS; ++st) {
    // prefetch next step's gate inputs
    const __half* pn = pg + ((st + 1 < SS) ? (size_t)(BB * NHH * 1024) : 0);
    __half nx[4];
#pragma unroll
    for (int g = 0; g < 4; ++g) nx[g] = pn[g * 256 + d];

    const uint4* yv = (const uint4*)(ypub + cur * 256) + (par << 4);
    float aA0 = 0.f, aB0 = 0.f, aA1 = 0.f, aB1 = 0.f;
    float aA2 = 0.f, aB2 = 0.f, aA3 = 0.f, aB3 = 0.f;
#pragma unroll
    for (int j = 0; j < 16; ++j) {
      uint4 yq = yv[j];                   // y dims kbase+8j .. kbase+8j+7
      uint4 wf = wl4[j * 512 + t];        // gate1 weights (LDS)
      uint4 wz = wgh[(4 + j) * 512 + t];  // gate2 weights (L2 stream)
      uint4 wo = wgh[(20 + j) * 512 + t]; // gate3 weights (L2 stream)
      if (j < 12) {
        aA0 = fdot2u(wv[4 * j + 0], yq.x, aA0);
        aB0 = fdot2u(wv[4 * j + 1], yq.y, aB0);
        aA0 = fdot2u(wv[4 * j + 2], yq.z, aA0);
        aB0 = fdot2u(wv[4 * j + 3], yq.w, aB0);
      } else {
        uint4 wi = wgh[(j - 12) * 512 + t];
        aA0 = fdot2u(wi.x, yq.x, aA0);
        aB0 = fdot2u(wi.y, yq.y, aB0);
        aA0 = fdot2u(wi.z, yq.z, aA0);
        aB0 = fdot2u(wi.w, yq.w, aB0);
      }
      aA1 = fdot2u(wf.x, yq.x, aA1);
      aB1 = fdot2u(wf.y, yq.y, aB1);
      aA1 = fdot2u(wf.z, yq.z, aA1);
      aB1 = fdot2u(wf.w, yq.w, aB1);
      aA2 = fdot2u(wz.x, yq.x, aA2);
      aB2 = fdot2u(wz.y, yq.y, aB2);
      aA2 = fdot2u(wz.z, yq.z, aA2);
      aB2 = fdot2u(wz.w, yq.w, aB2);
      aA3 = fdot2u(wo.x, yq.x, aA3);
      aB3 = fdot2u(wo.y, yq.y, aB3);
      aA3 = fdot2u(wo.z, yq.z, aA3);
      aB3 = fdot2u(wo.w, yq.w, aB3);
    }

    // combine k-halves across the lane pair (even<->odd), all 4 gates
    float part0 = aA0 + aB0, part1 = aA1 + aB1;
    float part2 = aA2 + aB2, part3 = aA3 + aB3;
    float raw0 = part0 + __shfl_xor(part0, 1) + cx[0] + rbv[0];
    float raw1 = part1 + __shfl_xor(part1, 1) + cx[1] + rbv[1];
    float raw2 = part2 + __shfl_xor(part2, 1) + cx[2] + rbv[2];
    float raw3 = part3 + __shfl_xor(part3, 1) + cx[3] + rbv[3];

    // state update (redundant in both lanes of the pair)
    float iv = raw0, fv = raw1, zv = raw2, ov = raw3;
    float ea = __expf(-fabsf(fv));
    float ls = fminf(fv, 0.f) - __logf(1.f + ea);      // log_sigmoid(fv)
    float lfm = m + ls;
    float mn = fmaxf(iv, lfm);
    float ig = __expf(iv - mn);
    float fg = __expf(lfm - mn);
    float pz = __expf(-2.f * fabsf(zv));
    float tmag = __fdividef(1.f - pz, 1.f + pz);
    float th = (zv < 0.f) ? -tmag : tmag;              // tanh(zv)
    c = fg * c + ig * th;
    n = fg * n + ig;
    float og = __fdividef(1.f, 1.f + __expf(-ov));     // sigmoid(ov)
    float y = og * __fdividef(c, n);
    m = mn;

    if (par == 0) {
      out[out_base + (size_t)st * EE] = y;
      ypub[(cur ^ 1) * 256 + d] = __float2half(y);
    }
    __syncthreads();
    cur ^= 1;
    pg = pn;
#pragma unroll
    for (int g = 0; g < 4; ++g) cx[g] = __half2float(nx[g]);
  }
}

// ---------------------------------------------------------------------------
// GroupNorm over DH per (b,s,h), in place on out. One wave = one head.
// ---------------------------------------------------------------------------
__global__ __launch_bounds__(256) void groupnorm(
    float* __restrict__ y, const float* __restrict__ gnw)
{
  const int row = blockIdx.x;
  const int t = threadIdx.x;
  float4 v = ((const float4*)y)[(size_t)row * 256 + t];
  float s = v.x + v.y + v.z + v.w;
  float q = v.x * v.x + v.y * v.y + v.z * v.z + v.w * v.w;
#pragma unroll
  for (int mask = 1; mask < 64; mask <<= 1) {
    s += __shfl_xor(s, mask, 64);
    q += __shfl_xor(q, mask, 64);
  }
  float mu = s * (1.f / 256.f);
  float var = q * (1.f / 256.f) - mu * mu;
  float rs = rsqrtf(var + 1e-5f);
  float4 g = ((const float4*)gnw)[t];
  float4 o;
  o.x = (v.x - mu) * rs * g.x;
  o.y = (v.y - mu) * rs * g.y;
  o.z = (v.z - mu) * rs * g.z;
  o.w = (v.w - mu) * rs * g.w;
  ((float4*)y)[(size_t)row * 256 + t] = o;
}

extern "C" void kernel_launch(void* const* d_in, const int* in_sizes, int n_in,
                              void* d_out, int out_size, void* d_ws, size_t ws_size,
                              hipStream_t stream) {
  const float* x      = (const float*)d_in[0];
  const float* conv_w = (const float*)d_in[1];
  const float* conv_b = (const float*)d_in[2];
  const float* fgw    = (const float*)d_in[3];
  const float* igw    = (const float*)d_in[4];
  const float* zgw    = (const float*)d_in[5];
  const float* ogw    = (const float*)d_in[6];
  const float* rk     = (const float*)d_in[7];
  const float* rb     = (const float*)d_in[8];
  const float* gnw    = (const float*)d_in[9];
  float* out = (float*)d_out;
  __half* gx = (__half*)d_ws;                        // 134217728 B
  uint4* wpk = (uint4*)((char*)d_ws + 134217728);    // 1179648 B

  pack_w<<<288, 256, 0, stream>>>(rk, wpk);

  dim3 g1(256, 4, 4);
  gates_gemm2<<<g1, 256, 0, stream>>>(x, conv_w, conv_b, fgw, igw, zgw, ogw, gx);

  const int scan_lds = 131072 + 1024;
  (void)hipFuncSetAttribute(reinterpret_cast<const void*>(slstm_scan8),
                            hipFuncAttributeMaxDynamicSharedMemorySize, scan_lds);
  slstm_scan8<<<32, 512, scan_lds, stream>>>(rk, rb, gx, wpk, out);

  groupnorm<<<BB * SS, 256, 0, stream>>>(out, gnw);
}

// Round 19
// 3718.930 us; speedup vs baseline: 1.2418x; 1.1573x over previous
//
#include <hip/hip_runtime.h>
#include <hip/hip_fp16.h>

#define BB 8
#define SS 2048
#define EE 1024
#define NHH 4
#define DHH 256

typedef _Float16 f16x2 __attribute__((ext_vector_type(2)));
typedef _Float16 f16x8 __attribute__((ext_vector_type(8)));
typedef float f32x4 __attribute__((ext_vector_type(4)));

__device__ __forceinline__ __half2 u2h2(unsigned int u) {
  union { unsigned int u; __half2 h; } c; c.u = u; return c.h;
}
__device__ __forceinline__ unsigned int h2u(__half2 h) {
  union { unsigned int u; __half2 h; } c; c.h = h; return c.u;
}
__device__ __forceinline__ f16x2 u2f(unsigned int u) {
  union { unsigned int u; f16x2 f; } c; c.u = u; return c.f;
}
__device__ __forceinline__ unsigned int pack2(float a, float b) {
  f16x2 f; f.x = (_Float16)a; f.y = (_Float16)b;
  union { f16x2 f; unsigned int u; } c; c.f = f; return c.u;
}
__device__ __forceinline__ float fdot2u(unsigned int w, unsigned int y, float acc) {
#if __has_builtin(__builtin_amdgcn_fdot2)
  return __builtin_amdgcn_fdot2(u2f(w), u2f(y), acc, false);
#else
  __half2 a = u2h2(w), b = u2h2(y);
  return acc + __low2float(a) * __low2float(b) + __high2float(a) * __high2float(b);
#endif
}

// ---------------------------------------------------------------------------
// MEGA kernel: gemm (2048 WGs, 2 tiles each) + scan (32 WGs) + groupnorm
// (64 WGs) in ONE dispatch, overlapped via coarse chunk counters.
//   prog[c]  (c=0..7): gemm tiles done for s-chunk c (target 512)
//   sprog[c*8+b]: scan WGs of batch b done with chunk c (target 4 heads)
// Scan waits 8 times total (not per-step); GN waits once per (b,c).
// All spins have escape hatches -> no hangs, worst case absmax failure.
// Dynamic LDS 132096 B (scan layout; gemm uses 84736 of it; GN none).
// ---------------------------------------------------------------------------
__global__
__attribute__((amdgpu_flat_work_group_size(512, 512), amdgpu_waves_per_eu(1)))
void mega(
    const float* __restrict__ x, const float* __restrict__ conv_w,
    const float* __restrict__ conv_b,
    const float* __restrict__ fgw, const float* __restrict__ igw,
    const float* __restrict__ zgw, const float* __restrict__ ogw,
    const float* __restrict__ rk, const float* __restrict__ rb,
    const float* __restrict__ gnw,
    __half* __restrict__ gx, float* __restrict__ out,
    unsigned int* __restrict__ prog, unsigned int* __restrict__ sprog)
{
  extern __shared__ unsigned char sm[];
  const int bid = blockIdx.x;
  const int tid = threadIdx.x;

  if (bid >= 32 && bid < 32 + 2048) {
    // =============================== GEMM path ===============================
    // 512-thr block = two independent 256-thr halves, each one tile (mt,nt2,h).
    // mt-major tile order -> low-s chunks complete first.
    const int half = tid >> 8, ltid = tid & 255;
    const int ti = (bid - 32) * 2 + half;          // 0..4095
    const int mtg = ti >> 4;                       // 0..255
    const int rest = ti & 15;
    const int nt2 = rest >> 2, h = rest & 3;
    const int s0 = mtg << 3;
    const int n0 = nt2 << 7;

    unsigned char* base = sm + half * 42368;
    float* Xs = (float*)base;                          // [8][11][33] f32
    __half* As = (__half*)(base + 11648);              // [2][64][40]
    __half* Bs = (__half*)(base + 11648 + 10240);      // [2][128][40]

    const float* W0 = (n0 < 256) ? fgw : igw;
    const float* W1 = (n0 < 256) ? zgw : ogw;
    const int oobase = n0 & 255;

    const int lw = (tid >> 6) & 3, l = tid & 63;
    const int lrow = l & 15, kq = l >> 4;
    const int koff = kq << 3;

    f32x4 acc[2][2][4] = {};

    for (int d0 = 0; d0 < DHH; d0 += 32) {
      const int ebase = h * DHH + d0;

      for (int i = ltid; i < 8 * 11 * 32; i += 256) {
        int kk = i & 31, rest2 = i >> 5;
        int b = rest2 / 11, si = rest2 - b * 11;
        int sg = s0 - 3 + si;
        float v = 0.f;
        if (sg >= 0) v = x[((size_t)b * SS + sg) * EE + ebase + kk];
        Xs[(b * 11 + si) * 33 + kk] = v;
      }
      for (int i = ltid; i < 2 * 128 * 32; i += 256) {
        int p = i >> 12;
        int rem = i & 4095;
        int col = rem >> 5, k = rem & 31;
        const float* Wp = p ? W1 : W0;
        int oo = oobase + col;
        Bs[(p * 128 + col) * 40 + k] =
            __float2half(Wp[((size_t)h * DHH + oo) * DHH + d0 + k]);
      }
      __syncthreads();

      for (int i = ltid; i < 2 * 64 * 32; i += 256) {
        int p = i >> 11;
        int rem = i & 2047;
        int kk = rem & 31, r = rem >> 5;
        int sl = r >> 3, b = r & 7;
        if (p == 0) {
          int e = ebase + kk;
          float xc = conv_b[e];
          xc = fmaf(Xs[(b * 11 + sl + 0) * 33 + kk], conv_w[0 * EE + e], xc);
          xc = fmaf(Xs[(b * 11 + sl + 1) * 33 + kk], conv_w[1 * EE + e], xc);
          xc = fmaf(Xs[(b * 11 + sl + 2) * 33 + kk], conv_w[2 * EE + e], xc);
          xc = fmaf(Xs[(b * 11 + sl + 3) * 33 + kk], conv_w[3 * EE + e], xc);
          float sg = 1.f / (1.f + __expf(-xc));
          As[(0 * 64 + r) * 40 + kk] = __float2half(xc * sg);
        } else {
          As[(1 * 64 + r) * 40 + kk] = __float2half(Xs[(b * 11 + sl + 3) * 33 + kk]);
        }
      }
      __syncthreads();

#pragma unroll
      for (int p = 0; p < 2; ++p) {
#pragma unroll
        for (int ct = 0; ct < 2; ++ct) {
          f16x8 bfrag = *(const f16x8*)&Bs[(p * 128 + lw * 32 + ct * 16 + lrow) * 40 + koff];
#pragma unroll
          for (int mtl = 0; mtl < 4; ++mtl) {
            f16x8 afrag = *(const f16x8*)&As[(p * 64 + mtl * 16 + lrow) * 40 + koff];
            acc[p][ct][mtl] =
                __builtin_amdgcn_mfma_f32_16x16x32_f16(afrag, bfrag, acc[p][ct][mtl], 0, 0, 0);
          }
        }
      }
      __syncthreads();
    }

#pragma unroll
    for (int p = 0; p < 2; ++p) {
#pragma unroll
      for (int ct = 0; ct < 2; ++ct) {
#pragma unroll
        for (int mtl = 0; mtl < 4; ++mtl) {
#pragma unroll
          for (int j = 0; j < 4; ++j) {
            int row_loc = mtl * 16 + kq * 4 + j;
            int grow = mtg * 64 + row_loc;
            int colg = n0 + lw * 32 + ct * 16 + lrow;
            gx[(size_t)grow * 4096 + h * 1024 + p * 512 + colg] =
                __float2half(acc[p][ct][mtl][j]);
          }
        }
      }
    }

    __syncthreads();   // all stores of both halves drained (vmcnt 0)
    if (ltid == 0)
      __hip_atomic_fetch_add(&prog[mtg >> 5], 1u,
                             __ATOMIC_RELEASE, __HIP_MEMORY_SCOPE_AGENT);
    return;
  }

  if (bid < 32) {
    // =============================== SCAN path ===============================
    // round-6 structure verbatim (session-best 3.40 ms) + chunk gating.
    uint4* wl4   = (uint4*)sm;                      // [16][512]
    __half* ypub = (__half*)(sm + 131072);          // [2][256]

    const int t = tid;
    const int b = bid >> 2, h = bid & 3;
    const int d = t >> 1, par = t & 1;
    const int kbase = par << 7;
    const float* Rh = rk + (size_t)h * DHH * 1024;

    unsigned int wv[3][64];
#pragma unroll
    for (int g = 0; g < 3; ++g) {
      const int col = g * 256 + d;
#pragma unroll
      for (int pp = 0; pp < 64; ++pp) {
        int k = kbase + 2 * pp;
        wv[g][pp] = pack2(Rh[(size_t)k * 1024 + col], Rh[(size_t)(k + 1) * 1024 + col]);
      }
    }
    {
      const int col = 3 * 256 + d;
      for (int q = 0; q < 16; ++q) {
        uint4 u;
        int k = kbase + 8 * q;
        u.x = pack2(Rh[(size_t)(k + 0) * 1024 + col], Rh[(size_t)(k + 1) * 1024 + col]);
        u.y = pack2(Rh[(size_t)(k + 2) * 1024 + col], Rh[(size_t)(k + 3) * 1024 + col]);
        u.z = pack2(Rh[(size_t)(k + 4) * 1024 + col], Rh[(size_t)(k + 5) * 1024 + col]);
        u.w = pack2(Rh[(size_t)(k + 6) * 1024 + col], Rh[(size_t)(k + 7) * 1024 + col]);
        wl4[q * 512 + t] = u;
      }
    }

    float rbv[4];
#pragma unroll
    for (int g = 0; g < 4; ++g) rbv[g] = rb[h * 1024 + g * 256 + d];

    float c = 0.f, n = 0.f, m = 0.f;
    if (t < 256) { ypub[t] = __float2half(0.f); ypub[256 + t] = __float2half(0.f); }
    __syncthreads();

    // wait for gemm chunk 0 (covers gx steps 0..255)
    if (t == 0) {
      int it = 0;
      while (__hip_atomic_load(&prog[0], __ATOMIC_ACQUIRE,
                               __HIP_MEMORY_SCOPE_AGENT) < 512u) {
        __builtin_amdgcn_s_sleep(8);
        if (++it > (1 << 20)) break;
      }
    }
    __syncthreads();
    int curc = 0;

    int cur = 0;
    const __half* pg = gx + ((size_t)b * NHH + h) * 1024;
    float cx[4];
#pragma unroll
    for (int g = 0; g < 4; ++g) cx[g] = __half2float(pg[g * 256 + d]);
    const size_t out_base = ((size_t)b * SS) * EE + h * DHH + d;

    for (int st = 0; st < SS; ++st) {
      // gate on gemm progress for step st+1 (the in-loop prefetch target)
      {
        int needc = ((st + 1 < SS) ? st + 1 : SS - 1) >> 8;
        if (needc != curc) {
          if (t == 0) {
            int it = 0;
            while (__hip_atomic_load(&prog[needc], __ATOMIC_ACQUIRE,
                                     __HIP_MEMORY_SCOPE_AGENT) < 512u) {
              __builtin_amdgcn_s_sleep(8);
              if (++it > (1 << 20)) break;
            }
          }
          __syncthreads();
          curc = needc;
        }
      }

      const __half* pn = pg + ((st + 1 < SS) ? (size_t)(BB * NHH * 1024) : 0);
      __half nx[4];
#pragma unroll
      for (int g = 0; g < 4; ++g) nx[g] = pn[g * 256 + d];

      const uint4* yv = (const uint4*)(ypub + cur * 256) + (par << 4);
      float aA0 = 0.f, aB0 = 0.f, aA1 = 0.f, aB1 = 0.f;
      float aA2 = 0.f, aB2 = 0.f, aA3 = 0.f, aB3 = 0.f;
#pragma unroll
      for (int j = 0; j < 16; ++j) {
        uint4 yq = yv[j];
        uint4 wq = wl4[j * 512 + t];
        aA0 = fdot2u(wv[0][4 * j + 0], yq.x, aA0);
        aA1 = fdot2u(wv[1][4 * j + 0], yq.x, aA1);
        aA2 = fdot2u(wv[2][4 * j + 0], yq.x, aA2);
        aA3 = fdot2u(wq.x,             yq.x, aA3);
        aB0 = fdot2u(wv[0][4 * j + 1], yq.y, aB0);
        aB1 = fdot2u(wv[1][4 * j + 1], yq.y, aB1);
        aB2 = fdot2u(wv[2][4 * j + 1], yq.y, aB2);
        aB3 = fdot2u(wq.y,             yq.y, aB3);
        aA0 = fdot2u(wv[0][4 * j + 2], yq.z, aA0);
        aA1 = fdot2u(wv[1][4 * j + 2], yq.z, aA1);
        aA2 = fdot2u(wv[2][4 * j + 2], yq.z, aA2);
        aA3 = fdot2u(wq.z,             yq.z, aA3);
        aB0 = fdot2u(wv[0][4 * j + 3], yq.w, aB0);
        aB1 = fdot2u(wv[1][4 * j + 3], yq.w, aB1);
        aB2 = fdot2u(wv[2][4 * j + 3], yq.w, aB2);
        aB3 = fdot2u(wq.w,             yq.w, aB3);
      }

      float part0 = aA0 + aB0, part1 = aA1 + aB1;
      float part2 = aA2 + aB2, part3 = aA3 + aB3;
      float raw0 = part0 + __shfl_xor(part0, 1) + cx[0] + rbv[0];
      float raw1 = part1 + __shfl_xor(part1, 1) + cx[1] + rbv[1];
      float raw2 = part2 + __shfl_xor(part2, 1) + cx[2] + rbv[2];
      float raw3 = part3 + __shfl_xor(part3, 1) + cx[3] + rbv[3];

      float iv = raw0, fv = raw1, zv = raw2, ov = raw3;
      float ea = __expf(-fabsf(fv));
      float ls = fminf(fv, 0.f) - __logf(1.f + ea);      // log_sigmoid(fv)
      float lfm = m + ls;
      float mn = fmaxf(iv, lfm);
      float ig = __expf(iv - mn);
      float fg = __expf(lfm - mn);
      float pz = __expf(-2.f * fabsf(zv));
      float tmag = __fdividef(1.f - pz, 1.f + pz);
      float th = (zv < 0.f) ? -tmag : tmag;              // tanh(zv)
      c = fg * c + ig * th;
      n = fg * n + ig;
      float og = __fdividef(1.f, 1.f + __expf(-ov));     // sigmoid(ov)
      float y = og * __fdividef(c, n);
      m = mn;

      if (par == 0) {
        out[out_base + (size_t)st * EE] = y;
        ypub[(cur ^ 1) * 256 + d] = __float2half(y);
      }
      __syncthreads();

      // publish chunk completion for GN (once per 256 steps)
      if ((st & 255) == 255 && t == 0) {
        __hip_atomic_fetch_add(&sprog[(st >> 8) * 8 + b], 1u,
                               __ATOMIC_RELEASE, __HIP_MEMORY_SCOPE_AGENT);
      }

      cur ^= 1;
      pg = pn;
#pragma unroll
      for (int g = 0; g < 4; ++g) cx[g] = __half2float(nx[g]);
    }
    return;
  }

  // =============================== GN path ===============================
  {
    const int g = bid - (32 + 2048);      // 0..63
    const int cchunk = g >> 3, b = g & 7;
    const int half = tid >> 8, tt = tid & 255;

    if (tid == 0) {
      int it = 0;
      while (__hip_atomic_load(&sprog[cchunk * 8 + b], __ATOMIC_ACQUIRE,
                               __HIP_MEMORY_SCOPE_AGENT) < 4u) {
        __builtin_amdgcn_s_sleep(16);
        if (++it > (1 << 20)) break;
      }
    }
    __syncthreads();

    for (int sr = 0; sr < 256; sr += 2) {
      const int s = cchunk * 256 + sr + half;
      const size_t row = (size_t)b * SS + s;
      float4 v = ((const float4*)out)[row * 256 + tt];
      float sacc = v.x + v.y + v.z + v.w;
      float qacc = v.x * v.x + v.y * v.y + v.z * v.z + v.w * v.w;
#pragma unroll
      for (int mask = 1; mask < 64; mask <<= 1) {
        sacc += __shfl_xor(sacc, mask, 64);
        qacc += __shfl_xor(qacc, mask, 64);
      }
      float mu = sacc * (1.f / 256.f);
      float var = qacc * (1.f / 256.f) - mu * mu;
      float rs = rsqrtf(var + 1e-5f);
      float4 gw = ((const float4*)gnw)[tt];
      float4 o;
      o.x = (v.x - mu) * rs * gw.x;
      o.y = (v.y - mu) * rs * gw.y;
      o.z = (v.z - mu) * rs * gw.z;
      o.w = (v.w - mu) * rs * gw.w;
      ((float4*)out)[row * 256 + tt] = o;
    }
  }
}

extern "C" void kernel_launch(void* const* d_in, const int* in_sizes, int n_in,
                              void* d_out, int out_size, void* d_ws, size_t ws_size,
                              hipStream_t stream) {
  const float* x      = (const float*)d_in[0];
  const float* conv_w = (const float*)d_in[1];
  const float* conv_b = (const float*)d_in[2];
  const float* fgw    = (const float*)d_in[3];
  const float* igw    = (const float*)d_in[4];
  const float* zgw    = (const float*)d_in[5];
  const float* ogw    = (const float*)d_in[6];
  const float* rk     = (const float*)d_in[7];
  const float* rb     = (const float*)d_in[8];
  const float* gnw    = (const float*)d_in[9];
  float* out = (float*)d_out;

  __half* gx = (__half*)d_ws;                                      // 134217728 B
  unsigned int* prog  = (unsigned int*)((char*)d_ws + 134217728);  // 32 B
  unsigned int* sprog = (unsigned int*)((char*)d_ws + 134217728 + 128); // 256 B

  (void)hipMemsetAsync(prog, 0, 4096, stream);

  const int lds = 132096;
  (void)hipFuncSetAttribute(reinterpret_cast<const void*>(mega),
                            hipFuncAttributeMaxDynamicSharedMemorySize, lds);
  mega<<<32 + 2048 + 64, 512, lds, stream>>>(
      x, conv_w, conv_b, fgw, igw, zgw, ogw, rk, rb, gnw, gx, out, prog, sprog);
}